// Round 5
// baseline (540.342 us; speedup 1.0000x reference)
//
#include <hip/hip_runtime.h>

// GCN 2-layer (R5): persistent mega-kernel, barrier FIXED vs R2.
// R2's bug: ACQUIRE load in the spin loop -> per-poll cache invalidate storm.
// R5 barrier: relaxed polls + one release fence before arrive, one acquire
// fence after flip; per-phase slots (no counter reset/reuse race).
// Phases (bodies byte-identical to R4's proven kernels):
//   P1-bucket | gemm1 -> bar -> per-bucket CSR -> bar ->
//   fused agg128+gemm2 (R4 decomposition: 16 nodes/block, wave=4 nodes) -> bar ->
//   agg64 -> d_out.
// Grid 1024 = 4 blocks/CU co-resident (LDS 34KB*4=136<=160KB, lb(256,4));
// R2 completed => co-residency holds. Bounded spin guard: fail, never hang.

#define TPB 256
#define NBKT 196        // ceil(50000/256) buckets of 256 nodes
#define EB_CAP 4608     // edge-buffer slots per bucket (mean 4096 + 8 sigma)
#define CSR_CAP 6400    // 4608 + 256*7 pad-to-8 worst case
#define P1_EPB 8192     // edges per P1 block
#define MEGA_GRID 1024  // 4 blocks/CU on 256 CUs; co-residency required

typedef __bf16 bf16x8 __attribute__((ext_vector_type(8)));
typedef __bf16 bf16x4 __attribute__((ext_vector_type(4)));
typedef __bf16 bf16x2 __attribute__((ext_vector_type(2)));
typedef float f32x4 __attribute__((ext_vector_type(4)));

__device__ __forceinline__ float bflo(unsigned u) { return __uint_as_float(u << 16); }
__device__ __forceinline__ float bfhi(unsigned u) { return __uint_as_float(u & 0xffff0000u); }

// ---------------- grid barrier: relaxed polls, single release/acquire fences ----------------
__device__ __forceinline__ void mega_bar(unsigned* slot, unsigned nblk) {
    __syncthreads();
    if (threadIdx.x == 0) {
        __builtin_amdgcn_fence(__ATOMIC_RELEASE, "agent");   // one wb: make my stores visible
        __hip_atomic_fetch_add(slot, 1u, __ATOMIC_RELAXED, __HIP_MEMORY_SCOPE_AGENT);
        int guard = 0;
        while (__hip_atomic_load(slot, __ATOMIC_RELAXED, __HIP_MEMORY_SCOPE_AGENT) < nblk) {
            __builtin_amdgcn_s_sleep(8);                     // no cache ops while polling
            if (++guard > (1 << 20)) break;                  // fail-safe: never hang
        }
        __builtin_amdgcn_fence(__ATOMIC_ACQUIRE, "agent");   // one inv: see others' stores
    }
    __syncthreads();
}

// ---------------- K0: clear gcnt+bar, zero sentinel rows, W frag pack ----------------
// A-frag (16x16x32): lane L holds A[m=L&15][k=(L>>4)*8+j]; A[m][k]=W[k][oct*16+m].
__global__ __launch_bounds__(256) void clear_wprep_kernel(
    unsigned* __restrict__ gcnt, float* __restrict__ dinv, __bf16* __restrict__ h2s,
    int N, unsigned* __restrict__ bar,
    const float* __restrict__ W1, const float* __restrict__ W2,
    __bf16* __restrict__ wf1, __bf16* __restrict__ wf2) {
    if (blockIdx.x == 0) {
        int t = threadIdx.x;
        if (t < NBKT) gcnt[t] = 0;
        if (t < 8) bar[t] = 0u;                           // per-phase barrier slots
        if (t == 0) dinv[N] = 0.0f;                       // sentinel weight
        if (t < 32) ((unsigned*)(h2s + (long)N * 64))[t] = 0u;  // sentinel row = 0
        return;
    }
    int g = (blockIdx.x - 1) * TPB + threadIdx.x;
    if (g < 64 * 64) {  // W1: K=256 (8 ksteps), OC=128 (8 octiles)
        int frag = g >> 6, L = g & 63;
        int kstep = frag >> 3, oct = frag & 7;
        int oc = oct * 16 + (L & 15);
        int k0 = kstep * 32 + (L >> 4) * 8;
        bf16x8 v;
#pragma unroll
        for (int j = 0; j < 8; j++) v[j] = (__bf16)W1[(k0 + j) * 128 + oc];
        ((bf16x8*)wf1)[g] = v;
    } else if (g < 64 * 64 + 16 * 64) {  // W2: K=128 (4), OC=64 (4)
        int g2 = g - 64 * 64;
        int frag = g2 >> 6, L = g2 & 63;
        int kstep = frag >> 2, oct = frag & 3;
        int oc = oct * 16 + (L & 15);
        int k0 = kstep * 32 + (L >> 4) * 8;
        bf16x8 v;
#pragma unroll
        for (int j = 0; j < 8; j++) v[j] = (__bf16)W2[(k0 + j) * 64 + oc];
        ((bf16x8*)wf2)[g2] = v;
    }
}

// ---------------- MFMA GEMM body (gemm1) ----------------
// out[r][oc] = (sum_k A[r][k]*W[k][oc]) * (SCALE ? dinv[r] : 1), bf16 out. Wave: 32 rows.
template <bool IN_BF16, int K, int OC, bool SCALE>
__device__ __forceinline__ void gemm_body(int bid, int tid, const void* __restrict__ Ain,
                                          const bf16x8* __restrict__ wfrag,
                                          const float* __restrict__ dinv,
                                          __bf16* __restrict__ outp, int M) {
    constexpr int KS = K / 32, OT = OC / 16;
    int wave = tid >> 6, lane = tid & 63;
    int col = lane & 15, q = lane >> 4;
    long rb = (long)bid * 128 + wave * 32;
    long r0 = rb + col, r1 = rb + 16 + col;
    long r0c = (r0 < M) ? r0 : (M - 1);
    long r1c = (r1 < M) ? r1 : (M - 1);

    f32x4 acc[OT][2];
#pragma unroll
    for (int o = 0; o < OT; o++) {
        acc[o][0] = (f32x4){0.f, 0.f, 0.f, 0.f};
        acc[o][1] = (f32x4){0.f, 0.f, 0.f, 0.f};
    }

#pragma unroll
    for (int ks = 0; ks < KS; ks++) {
        int k0 = ks * 32 + q * 8;
        bf16x8 b0, b1;
        if constexpr (IN_BF16) {
            const __bf16* A = (const __bf16*)Ain;
            b0 = *(const bf16x8*)(A + r0c * K + k0);
            b1 = *(const bf16x8*)(A + r1c * K + k0);
        } else {
            const float* A = (const float*)Ain;
            float4 f0a = *(const float4*)(A + r0c * K + k0);
            float4 f0b = *(const float4*)(A + r0c * K + k0 + 4);
            float4 f1a = *(const float4*)(A + r1c * K + k0);
            float4 f1b = *(const float4*)(A + r1c * K + k0 + 4);
            b0[0] = (__bf16)f0a.x; b0[1] = (__bf16)f0a.y; b0[2] = (__bf16)f0a.z; b0[3] = (__bf16)f0a.w;
            b0[4] = (__bf16)f0b.x; b0[5] = (__bf16)f0b.y; b0[6] = (__bf16)f0b.z; b0[7] = (__bf16)f0b.w;
            b1[0] = (__bf16)f1a.x; b1[1] = (__bf16)f1a.y; b1[2] = (__bf16)f1a.z; b1[3] = (__bf16)f1a.w;
            b1[4] = (__bf16)f1b.x; b1[5] = (__bf16)f1b.y; b1[6] = (__bf16)f1b.z; b1[7] = (__bf16)f1b.w;
        }
#pragma unroll
        for (int ot = 0; ot < OT; ot++) {
            bf16x8 a = wfrag[(ks * OT + ot) * 64 + lane];
            acc[ot][0] = __builtin_amdgcn_mfma_f32_16x16x32_bf16(a, b0, acc[ot][0], 0, 0, 0);
            acc[ot][1] = __builtin_amdgcn_mfma_f32_16x16x32_bf16(a, b1, acc[ot][1], 0, 0, 0);
        }
    }

    float sc0 = 1.f, sc1 = 1.f;
    if constexpr (SCALE) {
        sc0 = dinv[r0c];
        sc1 = dinv[r1c];
    }
#pragma unroll
    for (int ot = 0; ot < OT; ot++) {
        int oc = ot * 16 + q * 4;
        if (r0 < M) {
            bf16x4 v;
#pragma unroll
            for (int r = 0; r < 4; r++) v[r] = (__bf16)(acc[ot][0][r] * sc0);
            *(bf16x4*)(outp + r0 * OC + oc) = v;
        }
        if (r1 < M) {
            bf16x4 v;
#pragma unroll
            for (int r = 0; r < 4; r++) v[r] = (__bf16)(acc[ot][1][r] * sc1);
            *(bf16x4*)(outp + r1 * OC + oc) = v;
        }
    }
}

// ---------------- agg64 per-node body (h2s pre-scaled by dinv[row]) ----------------
#define ACC8B()                                                                            \
    do {                                                                                   \
        a0 += __uint_as_float((unsigned)v0 << 16); a1 += __uint_as_float((unsigned)v1 << 16); \
        a2 += __uint_as_float((unsigned)v2 << 16); a3 += __uint_as_float((unsigned)v3 << 16); \
        a0 += __uint_as_float((unsigned)v4 << 16); a1 += __uint_as_float((unsigned)v5 << 16); \
        a2 += __uint_as_float((unsigned)v6 << 16); a3 += __uint_as_float((unsigned)v7 << 16); \
    } while (0)

__device__ __forceinline__ void agg64_node(int n, int lane, const __bf16* __restrict__ hs,
                                           const int* __restrict__ csr,
                                           const int2* __restrict__ se,
                                           const float* __restrict__ dinv,
                                           const float* __restrict__ bias,
                                           float* __restrict__ outp) {
    int2 s_e = se[n];
    int start = s_e.x, m = s_e.y - s_e.x;    // m % 8 == 0
    float dn = dinv[n];
    const unsigned short* hp = (const unsigned short*)hs;  // row stride 64
    const int* sl = csr + start;
    float a0 = __uint_as_float(((unsigned)hp[(long)n * 64 + lane]) << 16);
    float a1 = 0.f, a2 = 0.f, a3 = 0.f;
    if (m > 0) {
        int4 c0 = *(const int4*)sl;
        int4 c1 = *(const int4*)(sl + 4);
        int i0 = __builtin_amdgcn_readfirstlane(c0.x);
        int i1 = __builtin_amdgcn_readfirstlane(c0.y);
        int i2 = __builtin_amdgcn_readfirstlane(c0.z);
        int i3 = __builtin_amdgcn_readfirstlane(c0.w);
        int i4 = __builtin_amdgcn_readfirstlane(c1.x);
        int i5 = __builtin_amdgcn_readfirstlane(c1.y);
        int i6 = __builtin_amdgcn_readfirstlane(c1.z);
        int i7 = __builtin_amdgcn_readfirstlane(c1.w);
        unsigned short v0 = hp[(long)i0 * 64 + lane], v1 = hp[(long)i1 * 64 + lane];
        unsigned short v2 = hp[(long)i2 * 64 + lane], v3 = hp[(long)i3 * 64 + lane];
        unsigned short v4 = hp[(long)i4 * 64 + lane], v5 = hp[(long)i5 * 64 + lane];
        unsigned short v6 = hp[(long)i6 * 64 + lane], v7 = hp[(long)i7 * 64 + lane];
        int4 d0 = *(const int4*)(sl + 8);
        int4 d1 = *(const int4*)(sl + 12);
        for (int j = 8; j < m; j += 8) {
            int t0 = __builtin_amdgcn_readfirstlane(d0.x);
            int t1 = __builtin_amdgcn_readfirstlane(d0.y);
            int t2 = __builtin_amdgcn_readfirstlane(d0.z);
            int t3 = __builtin_amdgcn_readfirstlane(d0.w);
            int t4 = __builtin_amdgcn_readfirstlane(d1.x);
            int t5 = __builtin_amdgcn_readfirstlane(d1.y);
            int t6 = __builtin_amdgcn_readfirstlane(d1.z);
            int t7 = __builtin_amdgcn_readfirstlane(d1.w);
            unsigned short u0 = hp[(long)t0 * 64 + lane], u1 = hp[(long)t1 * 64 + lane];
            unsigned short u2 = hp[(long)t2 * 64 + lane], u3 = hp[(long)t3 * 64 + lane];
            unsigned short u4 = hp[(long)t4 * 64 + lane], u5 = hp[(long)t5 * 64 + lane];
            unsigned short u6 = hp[(long)t6 * 64 + lane], u7 = hp[(long)t7 * 64 + lane];
            d0 = *(const int4*)(sl + j + 8);
            d1 = *(const int4*)(sl + j + 12);
            ACC8B();
            v0 = u0; v1 = u1; v2 = u2; v3 = u3; v4 = u4; v5 = u5; v6 = u6; v7 = u7;
        }
        ACC8B();
    }
    outp[(long)n * 64 + lane] = (a0 + a1 + a2 + a3) * dn + bias[lane];
}
#undef ACC8B

// ---------------- MEGA ----------------
#define ACC8()                                             \
    do {                                                   \
        a0x += bflo(v0) * w0; a0y += bfhi(v0) * w0;        \
        a1x += bflo(v1) * w1; a1y += bfhi(v1) * w1;        \
        a2x += bflo(v2) * w2; a2y += bfhi(v2) * w2;        \
        a3x += bflo(v3) * w3; a3y += bfhi(v3) * w3;        \
        a0x += bflo(v4) * w4; a0y += bfhi(v4) * w4;        \
        a1x += bflo(v5) * w5; a1y += bfhi(v5) * w5;        \
        a2x += bflo(v6) * w6; a2y += bfhi(v6) * w6;        \
        a3x += bflo(v7) * w7; a3y += bfhi(v7) * w7;        \
    } while (0)

__global__ __launch_bounds__(256, 4) void mega_kernel(
    const int* __restrict__ src, const int* __restrict__ dst, int E, int p1Blocks,
    int gemmBlocks, int k3Blocks,
    unsigned* __restrict__ gcnt, unsigned* __restrict__ ebuf,
    const float* __restrict__ x, const bf16x8* __restrict__ wf1, __bf16* __restrict__ h1u,
    int* __restrict__ csr, int2* __restrict__ se, float* __restrict__ dinv,
    const float* __restrict__ b1, const bf16x8* __restrict__ wf2,
    __bf16* __restrict__ h2s, const float* __restrict__ b2, float* __restrict__ outp,
    int N, unsigned* __restrict__ bar) {
    __shared__ unsigned sBuf[P1_EPB];  // 32 KB: sPacked (P1) / sEdges (CSR) / stash (K3)
    __shared__ int sCnt[256];
    __shared__ int sScan[256];
    int t = threadIdx.x;
    unsigned nblk = gridDim.x;
    int wave = t >> 6, lane = t & 63;

    // ---- phase 1: P1 bucket scatter | gemm1 (h1u = x @ W1, unscaled) ----
    for (int vb = (int)blockIdx.x; vb < p1Blocks + gemmBlocks; vb += (int)nblk) {
        if (vb < p1Blocks) {
            sCnt[t] = 0;
            __syncthreads();
            long e0 = (long)vb * P1_EPB;
            int cnt = (int)(E - e0);
            if (cnt > P1_EPB) cnt = P1_EPB;
            for (int i = t; i < cnt; i += 256) {
                unsigned s = (unsigned)src[e0 + i];
                unsigned d = (unsigned)dst[e0 + i];
                sBuf[i] = (s << 16) | d;             // both < 2^16
                atomicAdd(&sCnt[d >> 8], 1);
            }
            __syncthreads();
            int base = 0;
            if (t < NBKT) base = (int)atomicAdd(&gcnt[t], (unsigned)sCnt[t]);
            __syncthreads();
            if (t < NBKT) sCnt[t] = t * EB_CAP + base;   // global cursor
            __syncthreads();
            for (int i = t; i < cnt; i += 256) {
                unsigned p = sBuf[i];
                int b = (int)((p & 0xffffu) >> 8);
                int pos = atomicAdd(&sCnt[b], 1);
                if (pos < (b + 1) * EB_CAP) ebuf[pos] = p;
            }
            __syncthreads();
        } else {
            gemm_body<false, 256, 128, false>(vb - p1Blocks, t, x, wf1, nullptr, h1u, N);
        }
    }
    mega_bar(bar + 0, nblk);

    // ---- phase 2: per-bucket dense CSR (runs padded to x8 with sentinel N) ----
    for (int b = (int)blockIdx.x; b < NBKT; b += (int)nblk) {
        int m = (int)gcnt[b];
        if (m > EB_CAP) m = EB_CAP;
        sCnt[t] = 0;
        __syncthreads();
        const unsigned* eb = ebuf + b * EB_CAP;
        for (int i = t; i < m; i += 256) {
            unsigned p = eb[i];
            sBuf[i] = p;
            atomicAdd(&sCnt[p & 255u], 1);
        }
        __syncthreads();
        int c = sCnt[t];
        int pad = (c + 7) & ~7;                 // pad run to multiple of 8
        sScan[t] = pad;
        __syncthreads();
        for (int off2 = 1; off2 < 256; off2 <<= 1) {
            int v = (t >= off2) ? sScan[t - off2] : 0;
            __syncthreads();
            sScan[t] += v;
            __syncthreads();
        }
        int start = b * CSR_CAP + sScan[t] - pad;   // exclusive scan; multiple of 8
        int node = (b << 8) + t;
        if (node < N) {
            se[node] = make_int2(start, start + pad);
            dinv[node] = rsqrtf((float)c + 1.0f);   // true degree (+1 self-loop)
        }
        __syncthreads();
        sCnt[t] = start;                         // reuse as cursor
        __syncthreads();
        for (int i = t; i < m; i += 256) {
            unsigned p = sBuf[i];
            int pos = atomicAdd(&sCnt[p & 255u], 1);
            csr[pos] = (int)(p >> 16);           // src
        }
        if (node < N) {
            for (int k = start + c; k < start + pad; k++) csr[k] = N;  // sentinel pad
        }
        __syncthreads();
    }
    mega_bar(bar + 1, nblk);

    // ---- phase 3: fused agg128 (+bias, relu) + gemm2 (*dinv) -> h2s ----
    {
        __bf16* stash = (__bf16*)sBuf;           // 16 x 132 bf16 = 4.2 KB
        unsigned* stw = (unsigned*)sBuf;         // dword view, row stride 66
        float2 bv = ((const float2*)b1)[lane];
        for (int vb = (int)blockIdx.x; vb < k3Blocks; vb += (int)nblk) {
            int n0 = vb * 16;
#pragma unroll 1
            for (int i = 0; i < 4; i++) {
                int n = n0 + wave * 4 + i;
                float ox = 0.f, oy = 0.f;
                if (n < N) {
                    int2 s_e = se[n];
                    int start = s_e.x, m = s_e.y - s_e.x;    // m % 8 == 0
                    float dn = dinv[n];
                    const unsigned* hp = (const unsigned*)h1u;
                    const int* sl = csr + start;
                    unsigned self = hp[(long)n * 64 + lane];
                    float a0x = bflo(self) * dn, a0y = bfhi(self) * dn;
                    float a1x = 0.f, a1y = 0.f, a2x = 0.f, a2y = 0.f, a3x = 0.f, a3y = 0.f;
                    if (m > 0) {
                        int4 c0 = *(const int4*)sl;
                        int4 c1 = *(const int4*)(sl + 4);
                        int i0 = __builtin_amdgcn_readfirstlane(c0.x);
                        int i1 = __builtin_amdgcn_readfirstlane(c0.y);
                        int i2 = __builtin_amdgcn_readfirstlane(c0.z);
                        int i3 = __builtin_amdgcn_readfirstlane(c0.w);
                        int i4 = __builtin_amdgcn_readfirstlane(c1.x);
                        int i5 = __builtin_amdgcn_readfirstlane(c1.y);
                        int i6 = __builtin_amdgcn_readfirstlane(c1.z);
                        int i7 = __builtin_amdgcn_readfirstlane(c1.w);
                        unsigned v0 = hp[(long)i0 * 64 + lane], v1 = hp[(long)i1 * 64 + lane];
                        unsigned v2 = hp[(long)i2 * 64 + lane], v3 = hp[(long)i3 * 64 + lane];
                        unsigned v4 = hp[(long)i4 * 64 + lane], v5 = hp[(long)i5 * 64 + lane];
                        unsigned v6 = hp[(long)i6 * 64 + lane], v7 = hp[(long)i7 * 64 + lane];
                        float w0 = dinv[i0], w1 = dinv[i1], w2 = dinv[i2], w3 = dinv[i3];
                        float w4 = dinv[i4], w5 = dinv[i5], w6 = dinv[i6], w7 = dinv[i7];
                        int4 d0 = *(const int4*)(sl + 8);   // safe over-read (se follows csr)
                        int4 d1 = *(const int4*)(sl + 12);
                        for (int j = 8; j < m; j += 8) {
                            int t0 = __builtin_amdgcn_readfirstlane(d0.x);
                            int t1 = __builtin_amdgcn_readfirstlane(d0.y);
                            int t2 = __builtin_amdgcn_readfirstlane(d0.z);
                            int t3 = __builtin_amdgcn_readfirstlane(d0.w);
                            int t4 = __builtin_amdgcn_readfirstlane(d1.x);
                            int t5 = __builtin_amdgcn_readfirstlane(d1.y);
                            int t6 = __builtin_amdgcn_readfirstlane(d1.z);
                            int t7 = __builtin_amdgcn_readfirstlane(d1.w);
                            unsigned u0 = hp[(long)t0 * 64 + lane], u1 = hp[(long)t1 * 64 + lane];
                            unsigned u2 = hp[(long)t2 * 64 + lane], u3 = hp[(long)t3 * 64 + lane];
                            unsigned u4 = hp[(long)t4 * 64 + lane], u5 = hp[(long)t5 * 64 + lane];
                            unsigned u6 = hp[(long)t6 * 64 + lane], u7 = hp[(long)t7 * 64 + lane];
                            float q0 = dinv[t0], q1 = dinv[t1], q2 = dinv[t2], q3 = dinv[t3];
                            float q4 = dinv[t4], q5 = dinv[t5], q6 = dinv[t6], q7 = dinv[t7];
                            d0 = *(const int4*)(sl + j + 8);
                            d1 = *(const int4*)(sl + j + 12);
                            ACC8();
                            v0 = u0; v1 = u1; v2 = u2; v3 = u3; v4 = u4; v5 = u5; v6 = u6; v7 = u7;
                            w0 = q0; w1 = q1; w2 = q2; w3 = q3; w4 = q4; w5 = q5; w6 = q6; w7 = q7;
                        }
                        ACC8();
                    }
                    ox = fmaxf((a0x + a1x + a2x + a3x) * dn + bv.x, 0.f);
                    oy = fmaxf((a0y + a1y + a2y + a3y) * dn + bv.y, 0.f);
                }
                bf16x2 st = {(__bf16)ox, (__bf16)oy};
                stw[(wave * 4 + i) * 66 + lane] = *(unsigned*)&st;  // conflict-free
            }
            __syncthreads();
            // gemm2 from LDS: rows = 16 stashed nodes (B), wave w -> octile w of wf2 (A)
            int col = lane & 15, q = lane >> 4;
            const __bf16* srow = stash + col * 132;
            f32x4 acc = (f32x4){0.f, 0.f, 0.f, 0.f};
#pragma unroll
            for (int ks = 0; ks < 4; ks++) {
                bf16x8 bb = *(const bf16x8*)(srow + ks * 32 + q * 8);
                bf16x8 a = wf2[(ks * 4 + wave) * 64 + lane];
                acc = __builtin_amdgcn_mfma_f32_16x16x32_bf16(a, bb, acc, 0, 0, 0);
            }
            int node = n0 + col;
            if (node < N) {
                float dn2 = dinv[node];
                bf16x4 v;
#pragma unroll
                for (int r = 0; r < 4; r++) v[r] = (__bf16)(acc[r] * dn2);
                *(bf16x4*)(h2s + (long)node * 64 + (wave * 16 + q * 4)) = v;
            }
            __syncthreads();  // stash reused next vb iteration
        }
    }
    mega_bar(bar + 2, nblk);

    // ---- phase 4: agg64 -> d_out (fp32) ----
    for (int n = (int)blockIdx.x * 4 + wave; n < N; n += (int)nblk * 4)
        agg64_node(n, lane, h2s, csr, se, dinv, b2, outp);
}
#undef ACC8

static inline int cdiv(long a, long b) { return (int)((a + b - 1) / b); }

extern "C" void kernel_launch(void* const* d_in, const int* in_sizes, int n_in,
                              void* d_out, int out_size, void* d_ws, size_t ws_size,
                              hipStream_t stream) {
    const float* x  = (const float*)d_in[0];
    const int*   ei = (const int*)d_in[1];
    const float* W1 = (const float*)d_in[2];
    const float* b1 = (const float*)d_in[3];
    const float* W2 = (const float*)d_in[4];
    const float* b2 = (const float*)d_in[5];

    const int IN_C = 256;
    const int N = in_sizes[0] / IN_C;   // 50000
    const int E = in_sizes[1] / 2;      // 800000
    const int* src = ei;
    const int* dst = ei + E;

    char* w = (char*)d_ws;
    size_t off = 0;
    auto alloc = [&](size_t bytes) { void* p = w + off; off = (off + bytes + 255) & ~255ull; return p; };
    __bf16*   h1u  = (__bf16*)alloc((size_t)(N + 1) * 128 * 2); // +sentinel row
    __bf16*   h2s  = (__bf16*)alloc((size_t)(N + 1) * 64 * 2);  // +sentinel row (zeroed)
    unsigned* ebuf = (unsigned*)alloc((size_t)NBKT * EB_CAP * 4);
    int*      csr  = (int*)alloc((size_t)NBKT * CSR_CAP * 4);
    int2*     se   = (int2*)alloc((size_t)N * 8);
    float*    dinv = (float*)alloc((size_t)(N + 1) * 4);        // +sentinel 0
    unsigned* gcnt = (unsigned*)alloc(NBKT * 4);
    unsigned* bar  = (unsigned*)alloc(256);                     // per-phase barrier slots
    __bf16*   wf1  = (__bf16*)alloc(64 * 64 * 8 * 2);
    __bf16*   wf2  = (__bf16*)alloc(16 * 64 * 8 * 2);

    // K0: clear bucket counters + barrier slots + sentinel rows + pack W frags
    int wprepBlocks = cdiv(64 * 64 + 16 * 64, TPB);  // 20
    clear_wprep_kernel<<<1 + wprepBlocks, TPB, 0, stream>>>(gcnt, dinv, h2s, N, bar,
                                                            W1, W2, wf1, wf2);

    // MEGA: P1|gemm1 -> CSR -> agg128+gemm2 -> agg64, 3 in-kernel barriers
    int p1Blocks = cdiv(E, P1_EPB);                  // 98
    int gemmBlocks = cdiv(N, 128);                   // 391
    int k3Blocks = cdiv(N, 16);                      // 3125
    mega_kernel<<<MEGA_GRID, TPB, 0, stream>>>(
        src, dst, E, p1Blocks, gemmBlocks, k3Blocks, gcnt, ebuf, x,
        (const bf16x8*)wf1, h1u, csr, se, dinv, b1, (const bf16x8*)wf2, h2s, b2,
        (float*)d_out, N, bar);
}

// Round 6
// 193.230 us; speedup vs baseline: 2.7964x; 2.7964x over previous
//
#include <hip/hip_runtime.h>

// GCN 2-layer (R6): 4 launches, K0 eliminated.
// - gemm1/gemm2 read W1/W2 fragments DIRECTLY from global (L2-resident; one
//   base reg + imm offsets) -> no weight pre-pack kernel.
// - P1 writes private per-(block,bucket) slices ebuf2[98][196][96] with
//   LDS-only cursors (single pass, no global atomics, no pre-zeroed gcnt).
// - K2 concatenates 98 chunks/bucket then builds the dense per-bucket CSR
//   (sentinel-padded runs, multiple of 8, pad src=N with dinv[N]=0).
// - Sentinels (dinv[N], h2s[N] row) set by K2 block 0.
// - K3 = R4's fused agg128+gemm2 (16 nodes/block, wave=4 nodes, LDS stash,
//   octile-split MFMA epilogue). K4 = agg64.
// Persistent/grid-barrier variants are dead: cross-XCD barrier arrivals
// serialize ~100us/barrier (R2/R5). Launch boundary ~15-30us each (R2/R5
// calibration) -> fewer launches is the lever.

#define TPB 256
#define NBKT 196        // ceil(50000/256) buckets of 256 nodes
#define P1_BLKS 98      // E/8192
#define PB_CAP 96       // per-(block,bucket) slots: mean 41.8 + 8.5 sigma
#define EB_CAP 4608     // per-bucket total: mean 4081 + 8 sigma
#define CSR_CAP 6400    // 4608 + 256*7 pad-to-8 worst case
#define P1_EPB 8192     // edges per P1 block

typedef __bf16 bf16x8 __attribute__((ext_vector_type(8)));
typedef __bf16 bf16x4 __attribute__((ext_vector_type(4)));
typedef __bf16 bf16x2 __attribute__((ext_vector_type(2)));
typedef float f32x4 __attribute__((ext_vector_type(4)));

__device__ __forceinline__ float bflo(unsigned u) { return __uint_as_float(u << 16); }
__device__ __forceinline__ float bfhi(unsigned u) { return __uint_as_float(u & 0xffff0000u); }

// ---------------- gemm1 body: h1u = x @ W1 (bf16 out), W1 frags direct ----------------
// A-frag (16x16x32): lane L holds A[m=L&15][k=(L>>4)*8+j]; A[m][k]=W1[k][ot*16+m].
__device__ __forceinline__ void gemm1_body(int bid, int tid, const float* __restrict__ x,
                                           const float* __restrict__ W1,
                                           __bf16* __restrict__ outp, int M) {
    int wave = tid >> 6, lane = tid & 63;
    int col = lane & 15, q = lane >> 4;
    long rb = (long)bid * 128 + wave * 32;
    long r0 = rb + col, r1 = rb + 16 + col;
    long r0c = (r0 < M) ? r0 : (M - 1);
    long r1c = (r1 < M) ? r1 : (M - 1);

    f32x4 acc[8][2];
#pragma unroll
    for (int o = 0; o < 8; o++) {
        acc[o][0] = (f32x4){0.f, 0.f, 0.f, 0.f};
        acc[o][1] = (f32x4){0.f, 0.f, 0.f, 0.f};
    }

#pragma unroll
    for (int ks = 0; ks < 8; ks++) {
        int k0 = ks * 32 + q * 8;
        const float* A0 = x + r0c * 256 + k0;
        const float* A1 = x + r1c * 256 + k0;
        float4 f0a = *(const float4*)A0;
        float4 f0b = *(const float4*)(A0 + 4);
        float4 f1a = *(const float4*)A1;
        float4 f1b = *(const float4*)(A1 + 4);
        bf16x8 b0, b1;
        b0[0] = (__bf16)f0a.x; b0[1] = (__bf16)f0a.y; b0[2] = (__bf16)f0a.z; b0[3] = (__bf16)f0a.w;
        b0[4] = (__bf16)f0b.x; b0[5] = (__bf16)f0b.y; b0[6] = (__bf16)f0b.z; b0[7] = (__bf16)f0b.w;
        b1[0] = (__bf16)f1a.x; b1[1] = (__bf16)f1a.y; b1[2] = (__bf16)f1a.z; b1[3] = (__bf16)f1a.w;
        b1[4] = (__bf16)f1b.x; b1[5] = (__bf16)f1b.y; b1[6] = (__bf16)f1b.z; b1[7] = (__bf16)f1b.w;
        const float* wp = W1 + (long)k0 * 128 + col;   // imm offsets: j*512B + ot*64B <= 4032B
#pragma unroll
        for (int ot = 0; ot < 8; ot++) {
            bf16x8 a;
#pragma unroll
            for (int j = 0; j < 8; j++) a[j] = (__bf16)wp[j * 128 + ot * 16];
            acc[ot][0] = __builtin_amdgcn_mfma_f32_16x16x32_bf16(a, b0, acc[ot][0], 0, 0, 0);
            acc[ot][1] = __builtin_amdgcn_mfma_f32_16x16x32_bf16(a, b1, acc[ot][1], 0, 0, 0);
        }
    }

#pragma unroll
    for (int ot = 0; ot < 8; ot++) {
        int oc = ot * 16 + q * 4;
        if (r0 < M) {
            bf16x4 v;
#pragma unroll
            for (int r = 0; r < 4; r++) v[r] = (__bf16)acc[ot][0][r];
            *(bf16x4*)(outp + r0 * 128 + oc) = v;
        }
        if (r1 < M) {
            bf16x4 v;
#pragma unroll
            for (int r = 0; r < 4; r++) v[r] = (__bf16)acc[ot][1][r];
            *(bf16x4*)(outp + r1 * 128 + oc) = v;
        }
    }
}

// ---------------- K1: P1 private-slice scatter (LDS cursors only) | gemm1 ----------------
__global__ __launch_bounds__(256) void p1_gemm1_kernel(
    const int* __restrict__ src, const int* __restrict__ dst, int E, int p1Blocks,
    unsigned* __restrict__ gcnt2, unsigned* __restrict__ ebuf2,
    const float* __restrict__ x, const float* __restrict__ W1,
    __bf16* __restrict__ h1u, int M) {
    __shared__ int sCnt[256];
    int bx = (int)blockIdx.x, t = threadIdx.x;
    if (bx < p1Blocks) {
        sCnt[t] = 0;
        __syncthreads();
        long e0 = (long)bx * P1_EPB;
        int cnt = (int)(E - e0);
        if (cnt > P1_EPB) cnt = P1_EPB;
        unsigned* myslice = ebuf2 + (long)bx * NBKT * PB_CAP;
        for (int i = t; i < cnt; i += 256) {
            unsigned s = (unsigned)src[e0 + i];
            unsigned d = (unsigned)dst[e0 + i];
            int b = (int)(d >> 8);
            int pos = atomicAdd(&sCnt[b], 1);
            if (pos < PB_CAP) myslice[b * PB_CAP + pos] = (s << 16) | d;  // both < 2^16
        }
        __syncthreads();
        if (t < NBKT) {
            int c = sCnt[t];
            gcnt2[bx * NBKT + t] = (unsigned)(c < PB_CAP ? c : PB_CAP);
        }
    } else {
        gemm1_body(bx - p1Blocks, t, x, W1, h1u, M);
    }
}

// ---------------- K2: concat chunks -> per-bucket dense CSR (pad x8, sentinel N) ----------------
__global__ __launch_bounds__(256) void csr_kernel(
    const unsigned* __restrict__ gcnt2, const unsigned* __restrict__ ebuf2,
    int* __restrict__ csr, int2* __restrict__ se, float* __restrict__ dinv,
    __bf16* __restrict__ h2s, int N) {
    __shared__ unsigned sEdges[EB_CAP];  // 18 KB
    __shared__ int sCnt[256];
    __shared__ int sScan[256];
    __shared__ int sTot;
    int b = blockIdx.x, t = threadIdx.x;
    if (b == 0) {  // sentinels (idempotent, no sync needed before use in K3/K4)
        if (t == 0) dinv[N] = 0.0f;
        if (t < 32) ((unsigned*)(h2s + (long)N * 64))[t] = 0u;  // sentinel row = 0
    }
    sCnt[t] = 0;
    if (t == 0) sTot = 0;
    __syncthreads();
    // concat the 98 per-block chunks for this bucket into sEdges (+ count per node)
    if (t < P1_BLKS) {
        int c = (int)gcnt2[t * NBKT + b];
        int pos = atomicAdd(&sTot, c);
        const unsigned* chunk = ebuf2 + ((long)t * NBKT + b) * PB_CAP;
        for (int i = 0; i < c; i++) {
            if (pos + i >= EB_CAP) break;
            unsigned p = chunk[i];
            sEdges[pos + i] = p;
            atomicAdd(&sCnt[p & 255u], 1);
        }
    }
    __syncthreads();
    int m = sTot;
    if (m > EB_CAP) m = EB_CAP;
    int c = sCnt[t];
    int pad = (c + 7) & ~7;                 // pad run to multiple of 8
    sScan[t] = pad;
    __syncthreads();
    for (int off = 1; off < 256; off <<= 1) {
        int v = (t >= off) ? sScan[t - off] : 0;
        __syncthreads();
        sScan[t] += v;
        __syncthreads();
    }
    int start = b * CSR_CAP + sScan[t] - pad;   // exclusive scan; multiple of 8
    int node = (b << 8) + t;
    if (node < N) {
        se[node] = make_int2(start, start + pad);  // loop extent = padded
        dinv[node] = rsqrtf((float)c + 1.0f);      // true degree (+1 self-loop)
    }
    __syncthreads();
    sCnt[t] = start;                         // reuse as cursor
    __syncthreads();
    for (int i = t; i < m; i += 256) {
        unsigned p = sEdges[i];
        int pos = atomicAdd(&sCnt[p & 255u], 1);
        csr[pos] = (int)(p >> 16);           // src
    }
    // sentinel-fill pad slots (dinv[N]=0 -> zero contribution)
    if (node < N) {
        for (int k = start + c; k < start + pad; k++) csr[k] = N;
    }
}

// ---------------- K3: agg128 (pipelined, scalarized) + fused gemm2 (W2 direct) ----------------
// Block = 16 nodes, wave = 4 nodes (serial). Stash relu'd bf16 rows in a
// block-shared 16x132 LDS tile -> syncthreads -> gemm2 split by octile:
// wave w computes oc-tile w (4 MFMA, K=128), scales dinv[row], stores h2s.
#define ACC8()                                             \
    do {                                                   \
        a0x += bflo(v0) * w0; a0y += bfhi(v0) * w0;        \
        a1x += bflo(v1) * w1; a1y += bfhi(v1) * w1;        \
        a2x += bflo(v2) * w2; a2y += bfhi(v2) * w2;        \
        a3x += bflo(v3) * w3; a3y += bfhi(v3) * w3;        \
        a0x += bflo(v4) * w4; a0y += bfhi(v4) * w4;        \
        a1x += bflo(v5) * w5; a1y += bfhi(v5) * w5;        \
        a2x += bflo(v6) * w6; a2y += bfhi(v6) * w6;        \
        a3x += bflo(v7) * w7; a3y += bfhi(v7) * w7;        \
    } while (0)

__global__ __launch_bounds__(256) void agg128_gemm2_kernel(
    const __bf16* __restrict__ h, const int* __restrict__ csr,
    const int2* __restrict__ se, const float* __restrict__ dinv,
    const float* __restrict__ bias, const float* __restrict__ W2,
    __bf16* __restrict__ h2s, int N) {
    __shared__ __bf16 stash[16 * 132];    // 16 rows x 132(pad) bf16 = 4.2 KB
    int wave = threadIdx.x >> 6, lane = threadIdx.x & 63;
    int n0 = blockIdx.x * 16;             // block's 16 nodes
    unsigned* stw = (unsigned*)stash;     // dword view, row stride 66 words

    float2 bv = ((const float2*)bias)[lane];
#pragma unroll 1
    for (int i = 0; i < 4; i++) {
        int n = n0 + wave * 4 + i;
        float ox = 0.f, oy = 0.f;
        if (n < N) {
            int2 s_e = se[n];
            int start = s_e.x, m = s_e.y - s_e.x;    // m % 8 == 0
            float dn = dinv[n];
            const unsigned* hp = (const unsigned*)h;  // 2 bf16/word, stride 64 words
            const int* sl = csr + start;              // 32B-aligned
            unsigned self = hp[(long)n * 64 + lane];
            float a0x = bflo(self) * dn, a0y = bfhi(self) * dn;  // *dn at end -> dinv^2
            float a1x = 0.f, a1y = 0.f, a2x = 0.f, a2y = 0.f, a3x = 0.f, a3y = 0.f;
            if (m > 0) {
                int4 c0 = *(const int4*)sl;
                int4 c1 = *(const int4*)(sl + 4);
                int i0 = __builtin_amdgcn_readfirstlane(c0.x);
                int i1 = __builtin_amdgcn_readfirstlane(c0.y);
                int i2 = __builtin_amdgcn_readfirstlane(c0.z);
                int i3 = __builtin_amdgcn_readfirstlane(c0.w);
                int i4 = __builtin_amdgcn_readfirstlane(c1.x);
                int i5 = __builtin_amdgcn_readfirstlane(c1.y);
                int i6 = __builtin_amdgcn_readfirstlane(c1.z);
                int i7 = __builtin_amdgcn_readfirstlane(c1.w);
                unsigned v0 = hp[(long)i0 * 64 + lane], v1 = hp[(long)i1 * 64 + lane];
                unsigned v2 = hp[(long)i2 * 64 + lane], v3 = hp[(long)i3 * 64 + lane];
                unsigned v4 = hp[(long)i4 * 64 + lane], v5 = hp[(long)i5 * 64 + lane];
                unsigned v6 = hp[(long)i6 * 64 + lane], v7 = hp[(long)i7 * 64 + lane];
                float w0 = dinv[i0], w1 = dinv[i1], w2 = dinv[i2], w3 = dinv[i3];
                float w4 = dinv[i4], w5 = dinv[i5], w6 = dinv[i6], w7 = dinv[i7];
                int4 d0 = *(const int4*)(sl + 8);   // safe over-read (se follows csr)
                int4 d1 = *(const int4*)(sl + 12);
                for (int j = 8; j < m; j += 8) {
                    int t0 = __builtin_amdgcn_readfirstlane(d0.x);
                    int t1 = __builtin_amdgcn_readfirstlane(d0.y);
                    int t2 = __builtin_amdgcn_readfirstlane(d0.z);
                    int t3 = __builtin_amdgcn_readfirstlane(d0.w);
                    int t4 = __builtin_amdgcn_readfirstlane(d1.x);
                    int t5 = __builtin_amdgcn_readfirstlane(d1.y);
                    int t6 = __builtin_amdgcn_readfirstlane(d1.z);
                    int t7 = __builtin_amdgcn_readfirstlane(d1.w);
                    unsigned u0 = hp[(long)t0 * 64 + lane], u1 = hp[(long)t1 * 64 + lane];
                    unsigned u2 = hp[(long)t2 * 64 + lane], u3 = hp[(long)t3 * 64 + lane];
                    unsigned u4 = hp[(long)t4 * 64 + lane], u5 = hp[(long)t5 * 64 + lane];
                    unsigned u6 = hp[(long)t6 * 64 + lane], u7 = hp[(long)t7 * 64 + lane];
                    float q0 = dinv[t0], q1 = dinv[t1], q2 = dinv[t2], q3 = dinv[t3];
                    float q4 = dinv[t4], q5 = dinv[t5], q6 = dinv[t6], q7 = dinv[t7];
                    d0 = *(const int4*)(sl + j + 8);
                    d1 = *(const int4*)(sl + j + 12);
                    ACC8();
                    v0 = u0; v1 = u1; v2 = u2; v3 = u3; v4 = u4; v5 = u5; v6 = u6; v7 = u7;
                    w0 = q0; w1 = q1; w2 = q2; w3 = q3; w4 = q4; w5 = q5; w6 = q6; w7 = q7;
                }
                ACC8();
            }
            ox = fmaxf((a0x + a1x + a2x + a3x) * dn + bv.x, 0.f);
            oy = fmaxf((a0y + a1y + a2y + a3y) * dn + bv.y, 0.f);
        }
        bf16x2 st = {(__bf16)ox, (__bf16)oy};  // invalid nodes stash zeros
        stw[(wave * 4 + i) * 66 + lane] = *(unsigned*)&st;  // conflict-free (measured 0)
    }
    __syncthreads();

    // gemm2 from LDS: rows = 16 stashed nodes (B), wave w -> octile w of W2 (A direct)
    int col = lane & 15, q = lane >> 4;
    const __bf16* srow = stash + col * 132;
    f32x4 acc = (f32x4){0.f, 0.f, 0.f, 0.f};
#pragma unroll
    for (int ks = 0; ks < 4; ks++) {
        bf16x8 bb = *(const bf16x8*)(srow + ks * 32 + q * 8);
        const float* wp = W2 + (long)(ks * 32 + q * 8) * 64 + wave * 16 + col;
        bf16x8 a;
#pragma unroll
        for (int j = 0; j < 8; j++) a[j] = (__bf16)wp[j * 64];
        acc = __builtin_amdgcn_mfma_f32_16x16x32_bf16(a, bb, acc, 0, 0, 0);
    }
    int node = n0 + col;
    if (node < N) {
        float dn2 = dinv[node];
        bf16x4 v;
#pragma unroll
        for (int r = 0; r < 4; r++) v[r] = (__bf16)(acc[r] * dn2);
        *(bf16x4*)(h2s + (long)node * 64 + (wave * 16 + q * 4)) = v;
    }
}
#undef ACC8

// ---------------- K4: agg64 (h2s pre-scaled by dinv[row]; sentinel row = 0) ----------------
// self term: h2s[n] already carries dinv[n]; final *dn gives dinv^2 (no extra *dn).
#define ACC8B()                                                                            \
    do {                                                                                   \
        a0 += __uint_as_float((unsigned)v0 << 16); a1 += __uint_as_float((unsigned)v1 << 16); \
        a2 += __uint_as_float((unsigned)v2 << 16); a3 += __uint_as_float((unsigned)v3 << 16); \
        a0 += __uint_as_float((unsigned)v4 << 16); a1 += __uint_as_float((unsigned)v5 << 16); \
        a2 += __uint_as_float((unsigned)v6 << 16); a3 += __uint_as_float((unsigned)v7 << 16); \
    } while (0)

__global__ __launch_bounds__(256) void agg64_kernel(const __bf16* __restrict__ hs,
                                                    const int* __restrict__ csr,
                                                    const int2* __restrict__ se,
                                                    const float* __restrict__ dinv,
                                                    const float* __restrict__ bias,
                                                    float* __restrict__ outp, int N) {
    int gid = blockIdx.x * TPB + threadIdx.x;
    int n = gid >> 6, lane = gid & 63;
    if (n >= N) return;
    int2 s_e = se[n];
    int start = s_e.x, m = s_e.y - s_e.x;    // m % 8 == 0
    float dn = dinv[n];
    const unsigned short* hp = (const unsigned short*)hs;  // row stride 64
    const int* sl = csr + start;
    float a0 = __uint_as_float(((unsigned)hp[(long)n * 64 + lane]) << 16);
    float a1 = 0.f, a2 = 0.f, a3 = 0.f;
    if (m > 0) {
        int4 c0 = *(const int4*)sl;
        int4 c1 = *(const int4*)(sl + 4);
        int i0 = __builtin_amdgcn_readfirstlane(c0.x);
        int i1 = __builtin_amdgcn_readfirstlane(c0.y);
        int i2 = __builtin_amdgcn_readfirstlane(c0.z);
        int i3 = __builtin_amdgcn_readfirstlane(c0.w);
        int i4 = __builtin_amdgcn_readfirstlane(c1.x);
        int i5 = __builtin_amdgcn_readfirstlane(c1.y);
        int i6 = __builtin_amdgcn_readfirstlane(c1.z);
        int i7 = __builtin_amdgcn_readfirstlane(c1.w);
        unsigned short v0 = hp[(long)i0 * 64 + lane], v1 = hp[(long)i1 * 64 + lane];
        unsigned short v2 = hp[(long)i2 * 64 + lane], v3 = hp[(long)i3 * 64 + lane];
        unsigned short v4 = hp[(long)i4 * 64 + lane], v5 = hp[(long)i5 * 64 + lane];
        unsigned short v6 = hp[(long)i6 * 64 + lane], v7 = hp[(long)i7 * 64 + lane];
        int4 d0 = *(const int4*)(sl + 8);
        int4 d1 = *(const int4*)(sl + 12);
        for (int j = 8; j < m; j += 8) {
            int t0 = __builtin_amdgcn_readfirstlane(d0.x);
            int t1 = __builtin_amdgcn_readfirstlane(d0.y);
            int t2 = __builtin_amdgcn_readfirstlane(d0.z);
            int t3 = __builtin_amdgcn_readfirstlane(d0.w);
            int t4 = __builtin_amdgcn_readfirstlane(d1.x);
            int t5 = __builtin_amdgcn_readfirstlane(d1.y);
            int t6 = __builtin_amdgcn_readfirstlane(d1.z);
            int t7 = __builtin_amdgcn_readfirstlane(d1.w);
            unsigned short u0 = hp[(long)t0 * 64 + lane], u1 = hp[(long)t1 * 64 + lane];
            unsigned short u2 = hp[(long)t2 * 64 + lane], u3 = hp[(long)t3 * 64 + lane];
            unsigned short u4 = hp[(long)t4 * 64 + lane], u5 = hp[(long)t5 * 64 + lane];
            unsigned short u6 = hp[(long)t6 * 64 + lane], u7 = hp[(long)t7 * 64 + lane];
            d0 = *(const int4*)(sl + j + 8);
            d1 = *(const int4*)(sl + j + 12);
            ACC8B();
            v0 = u0; v1 = u1; v2 = u2; v3 = u3; v4 = u4; v5 = u5; v6 = u6; v7 = u7;
        }
        ACC8B();
    }
    outp[(long)n * 64 + lane] = (a0 + a1 + a2 + a3) * dn + bias[lane];
}
#undef ACC8B

static inline int cdiv(long a, long b) { return (int)((a + b - 1) / b); }

extern "C" void kernel_launch(void* const* d_in, const int* in_sizes, int n_in,
                              void* d_out, int out_size, void* d_ws, size_t ws_size,
                              hipStream_t stream) {
    const float* x  = (const float*)d_in[0];
    const int*   ei = (const int*)d_in[1];
    const float* W1 = (const float*)d_in[2];
    const float* b1 = (const float*)d_in[3];
    const float* W2 = (const float*)d_in[4];
    const float* b2 = (const float*)d_in[5];

    const int IN_C = 256;
    const int N = in_sizes[0] / IN_C;   // 50000
    const int E = in_sizes[1] / 2;      // 800000
    const int* src = ei;
    const int* dst = ei + E;

    char* w = (char*)d_ws;
    size_t off = 0;
    auto alloc = [&](size_t bytes) { void* p = w + off; off = (off + bytes + 255) & ~255ull; return p; };
    __bf16*   h1u   = (__bf16*)alloc((size_t)(N + 1) * 128 * 2); // +sentinel row
    __bf16*   h2s   = (__bf16*)alloc((size_t)(N + 1) * 64 * 2);  // +sentinel row (zeroed by K2)
    unsigned* ebuf2 = (unsigned*)alloc((size_t)P1_BLKS * NBKT * PB_CAP * 4);  // 7.4 MB
    int*      csr   = (int*)alloc((size_t)NBKT * CSR_CAP * 4);
    int2*     se    = (int2*)alloc((size_t)N * 8);
    float*    dinv  = (float*)alloc((size_t)(N + 1) * 4);        // +sentinel 0
    unsigned* gcnt2 = (unsigned*)alloc((size_t)P1_BLKS * NBKT * 4);

    // K1: private-slice bucket scatter | gemm1 (h1u = x @ W1, W1 direct)
    int p1Blocks = P1_BLKS;                          // 98
    int gemmBlocks = cdiv(N, 128);                   // 391
    p1_gemm1_kernel<<<p1Blocks + gemmBlocks, TPB, 0, stream>>>(
        src, dst, E, p1Blocks, gcnt2, ebuf2, x, W1, h1u, N);

    // K2: concat chunks -> per-bucket dense CSR + dinv + sentinels
    csr_kernel<<<NBKT, TPB, 0, stream>>>(gcnt2, ebuf2, csr, se, dinv, h2s, N);

    // K3: layer-1 aggregate (+bias, relu) fused with gemm2 -> h2s
    agg128_gemm2_kernel<<<cdiv(N, 16), TPB, 0, stream>>>(h1u, csr, se, dinv, b1,
                                                         W2, h2s, N);

    // K4: layer-2 aggregate -> d_out (fp32)
    agg64_kernel<<<cdiv((long)N * 64, TPB), TPB, 0, stream>>>(h2s, csr, se, dinv, b2,
                                                              (float*)d_out, N);
}

// Round 7
// 179.370 us; speedup vs baseline: 3.0124x; 1.0773x over previous
//
#include <hip/hip_runtime.h>

// GCN 2-layer (R7) = R4 structure + K1 occupancy fix.
// R6 lesson: K1 was grid-starved (489 blocks = 1.9/CU, 13.7% occ) and its
// direct-W scalar frag loads were 8x the VMEM instrs. R7: packed W frags
// restored (K0 returns), gemm1 split to 64 rows/block (16 rows/wave) -> 782
// blocks, P1 split to 196 blocks x 4096 edges (LDS 33->17KB). 978-block K1.
// K0 clear+wprep -> K1 [P1-bucket | gemm1] -> K2 per-bucket CSR+dinv+pad ->
// K3 agg128+gemm2(*dinv) -> K4 agg64(+bias) -> d_out.
// Dead ends (measured): grid-barrier persistent kernels (R2/R5: cross-XCD
// barrier arrivals ~100us each); 16-nodes-per-wave fusion (R3: 25% occ).

#define TPB 256
#define NBKT 196        // ceil(50000/256) buckets of 256 nodes
#define EB_CAP 4608     // edge-buffer slots per bucket (mean 4096 + 8 sigma)
#define CSR_CAP 6400    // 4608 + 256*7 pad-to-8 worst case
#define P1_EPB 4096     // edges per P1 block (16 KB sPacked)

typedef __bf16 bf16x8 __attribute__((ext_vector_type(8)));
typedef __bf16 bf16x4 __attribute__((ext_vector_type(4)));
typedef __bf16 bf16x2 __attribute__((ext_vector_type(2)));
typedef float f32x4 __attribute__((ext_vector_type(4)));

__device__ __forceinline__ float bflo(unsigned u) { return __uint_as_float(u << 16); }
__device__ __forceinline__ float bfhi(unsigned u) { return __uint_as_float(u & 0xffff0000u); }

// ---------------- K0: clear gcnt, zero sentinel rows, W frag pack ----------------
// A-frag (16x16x32): lane L holds A[m=L&15][k=(L>>4)*8+j]; A[m][k]=W[k][oct*16+m].
__global__ __launch_bounds__(256) void clear_wprep_kernel(
    unsigned* __restrict__ gcnt, float* __restrict__ dinv, __bf16* __restrict__ h2s,
    int N,
    const float* __restrict__ W1, const float* __restrict__ W2,
    __bf16* __restrict__ wf1, __bf16* __restrict__ wf2) {
    if (blockIdx.x == 0) {
        int t = threadIdx.x;
        if (t < NBKT) gcnt[t] = 0;
        if (t == 0) dinv[N] = 0.0f;                       // sentinel weight
        if (t < 32) ((unsigned*)(h2s + (long)N * 64))[t] = 0u;  // sentinel row = 0
        return;
    }
    int g = (blockIdx.x - 1) * TPB + threadIdx.x;
    if (g < 64 * 64) {  // W1: K=256 (8 ksteps), OC=128 (8 octiles)
        int frag = g >> 6, L = g & 63;
        int kstep = frag >> 3, oct = frag & 7;
        int oc = oct * 16 + (L & 15);
        int k0 = kstep * 32 + (L >> 4) * 8;
        bf16x8 v;
#pragma unroll
        for (int j = 0; j < 8; j++) v[j] = (__bf16)W1[(k0 + j) * 128 + oc];
        ((bf16x8*)wf1)[g] = v;
    } else if (g < 64 * 64 + 16 * 64) {  // W2: K=128 (4), OC=64 (4)
        int g2 = g - 64 * 64;
        int frag = g2 >> 6, L = g2 & 63;
        int kstep = frag >> 2, oct = frag & 3;
        int oc = oct * 16 + (L & 15);
        int k0 = kstep * 32 + (L >> 4) * 8;
        bf16x8 v;
#pragma unroll
        for (int j = 0; j < 8; j++) v[j] = (__bf16)W2[(k0 + j) * 64 + oc];
        ((bf16x8*)wf2)[g2] = v;
    }
}

// ---------------- gemm1 body: 16 rows/wave, 64 rows/block (occupancy form) ----------------
// h1u[r][oc] = sum_k x[r][k]*W1[k][oc], bf16 out. 4 MFMA/row (same as 32-row form).
__device__ __forceinline__ void gemm1_body(int bid, int tid, const float* __restrict__ x,
                                           const bf16x8* __restrict__ wfrag,
                                           __bf16* __restrict__ outp, int M) {
    int wave = tid >> 6, lane = tid & 63;
    int col = lane & 15, q = lane >> 4;
    long r0 = (long)bid * 64 + wave * 16 + col;
    long r0c = (r0 < M) ? r0 : (M - 1);

    f32x4 acc[8];
#pragma unroll
    for (int o = 0; o < 8; o++) acc[o] = (f32x4){0.f, 0.f, 0.f, 0.f};

#pragma unroll
    for (int ks = 0; ks < 8; ks++) {
        int k0 = ks * 32 + q * 8;
        const float* A0 = x + r0c * 256 + k0;
        float4 f0a = *(const float4*)A0;
        float4 f0b = *(const float4*)(A0 + 4);
        bf16x8 b0;
        b0[0] = (__bf16)f0a.x; b0[1] = (__bf16)f0a.y; b0[2] = (__bf16)f0a.z; b0[3] = (__bf16)f0a.w;
        b0[4] = (__bf16)f0b.x; b0[5] = (__bf16)f0b.y; b0[6] = (__bf16)f0b.z; b0[7] = (__bf16)f0b.w;
#pragma unroll
        for (int ot = 0; ot < 8; ot++) {
            bf16x8 a = wfrag[(ks * 8 + ot) * 64 + lane];
            acc[ot] = __builtin_amdgcn_mfma_f32_16x16x32_bf16(a, b0, acc[ot], 0, 0, 0);
        }
    }

    if (r0 < M) {
#pragma unroll
        for (int ot = 0; ot < 8; ot++) {
            int oc = ot * 16 + q * 4;
            bf16x4 v;
#pragma unroll
            for (int r = 0; r < 4; r++) v[r] = (__bf16)acc[ot][r];
            *(bf16x4*)(outp + r0 * 128 + oc) = v;
        }
    }
}

// ---------------- K1: P1 bucket scatter (LDS two-pass) | gemm1 ----------------
__global__ __launch_bounds__(256) void p1_gemm1_kernel(
    const int* __restrict__ src, const int* __restrict__ dst, int E, int p1Blocks,
    unsigned* __restrict__ gcnt, unsigned* __restrict__ ebuf,
    const float* __restrict__ x, const bf16x8* __restrict__ wf1,
    __bf16* __restrict__ h1u, int M) {
    __shared__ unsigned sPacked[P1_EPB];  // 16 KB
    __shared__ int sCnt[256];
    if ((int)blockIdx.x < p1Blocks) {
        int t = threadIdx.x;
        sCnt[t] = 0;
        __syncthreads();
        long e0 = (long)blockIdx.x * P1_EPB;
        int cnt = (int)(E - e0);
        if (cnt > P1_EPB) cnt = P1_EPB;
        for (int i = t; i < cnt; i += 256) {
            unsigned s = (unsigned)src[e0 + i];
            unsigned d = (unsigned)dst[e0 + i];
            sPacked[i] = (s << 16) | d;          // both < 2^16
            atomicAdd(&sCnt[d >> 8], 1);
        }
        __syncthreads();
        int base = 0;
        if (t < NBKT) base = (int)atomicAdd(&gcnt[t], (unsigned)sCnt[t]);
        __syncthreads();
        if (t < NBKT) sCnt[t] = t * EB_CAP + base;   // global cursor
        __syncthreads();
        for (int i = t; i < cnt; i += 256) {
            unsigned p = sPacked[i];
            int b = (int)((p & 0xffffu) >> 8);
            int pos = atomicAdd(&sCnt[b], 1);
            if (pos < (b + 1) * EB_CAP) ebuf[pos] = p;
        }
    } else {
        gemm1_body(blockIdx.x - p1Blocks, threadIdx.x, x, wf1, h1u, M);
    }
}

// ---------------- K2: per-bucket dense CSR (runs padded to x8 with sentinel N) ----------------
__global__ __launch_bounds__(256) void csr_kernel(
    const unsigned* __restrict__ gcnt, const unsigned* __restrict__ ebuf,
    int* __restrict__ csr, int2* __restrict__ se, float* __restrict__ dinv, int N) {
    __shared__ unsigned sEdges[EB_CAP];  // 18 KB
    __shared__ int sCnt[256];
    __shared__ int sScan[256];
    int b = blockIdx.x, t = threadIdx.x;
    int m = (int)gcnt[b];
    if (m > EB_CAP) m = EB_CAP;
    sCnt[t] = 0;
    __syncthreads();
    const unsigned* eb = ebuf + b * EB_CAP;
    for (int i = t; i < m; i += 256) {
        unsigned p = eb[i];
        sEdges[i] = p;
        atomicAdd(&sCnt[p & 255u], 1);
    }
    __syncthreads();
    int c = sCnt[t];
    int pad = (c + 7) & ~7;                 // pad run to multiple of 8
    sScan[t] = pad;
    __syncthreads();
    for (int off = 1; off < 256; off <<= 1) {
        int v = (t >= off) ? sScan[t - off] : 0;
        __syncthreads();
        sScan[t] += v;
        __syncthreads();
    }
    int start = b * CSR_CAP + sScan[t] - pad;   // exclusive scan; multiple of 8
    int node = (b << 8) + t;
    if (node < N) {
        se[node] = make_int2(start, start + pad);  // loop extent = padded
        dinv[node] = rsqrtf((float)c + 1.0f);      // true degree (+1 self-loop)
    }
    __syncthreads();
    sCnt[t] = start;                         // reuse as cursor
    __syncthreads();
    for (int i = t; i < m; i += 256) {
        unsigned p = sEdges[i];
        int pos = atomicAdd(&sCnt[p & 255u], 1);
        csr[pos] = (int)(p >> 16);           // src
    }
    // sentinel-fill pad slots (dinv[N]=0 -> zero contribution)
    if (node < N) {
        for (int k = start + c; k < start + pad; k++) csr[k] = N;
    }
}

// ---------------- K3: agg128 (pipelined, scalarized) + fused gemm2 ----------------
// Block = 16 nodes, wave = 4 nodes (serial). Stash relu'd bf16 rows in a
// block-shared 16x132 LDS tile -> syncthreads -> gemm2 split by octile:
// wave w computes oc-tile w (4 MFMA, K=128), scales dinv[row], stores h2s.
#define ACC8()                                             \
    do {                                                   \
        a0x += bflo(v0) * w0; a0y += bfhi(v0) * w0;        \
        a1x += bflo(v1) * w1; a1y += bfhi(v1) * w1;        \
        a2x += bflo(v2) * w2; a2y += bfhi(v2) * w2;        \
        a3x += bflo(v3) * w3; a3y += bfhi(v3) * w3;        \
        a0x += bflo(v4) * w4; a0y += bfhi(v4) * w4;        \
        a1x += bflo(v5) * w5; a1y += bfhi(v5) * w5;        \
        a2x += bflo(v6) * w6; a2y += bfhi(v6) * w6;        \
        a3x += bflo(v7) * w7; a3y += bfhi(v7) * w7;        \
    } while (0)

__global__ __launch_bounds__(256) void agg128_gemm2_kernel(
    const __bf16* __restrict__ h, const int* __restrict__ csr,
    const int2* __restrict__ se, const float* __restrict__ dinv,
    const float* __restrict__ bias, const bf16x8* __restrict__ wf2,
    __bf16* __restrict__ h2s, int N) {
    __shared__ __bf16 stash[16 * 132];    // 16 rows x 132(pad) bf16 = 4.2 KB
    int wave = threadIdx.x >> 6, lane = threadIdx.x & 63;
    int n0 = blockIdx.x * 16;             // block's 16 nodes
    unsigned* stw = (unsigned*)stash;     // dword view, row stride 66 words

    float2 bv = ((const float2*)bias)[lane];
#pragma unroll 1
    for (int i = 0; i < 4; i++) {
        int n = n0 + wave * 4 + i;
        float ox = 0.f, oy = 0.f;
        if (n < N) {
            int2 s_e = se[n];
            int start = s_e.x, m = s_e.y - s_e.x;    // m % 8 == 0
            float dn = dinv[n];
            const unsigned* hp = (const unsigned*)h;  // 2 bf16/word, stride 64 words
            const int* sl = csr + start;              // 32B-aligned
            unsigned self = hp[(long)n * 64 + lane];
            float a0x = bflo(self) * dn, a0y = bfhi(self) * dn;  // *dn at end -> dinv^2
            float a1x = 0.f, a1y = 0.f, a2x = 0.f, a2y = 0.f, a3x = 0.f, a3y = 0.f;
            if (m > 0) {
                int4 c0 = *(const int4*)sl;
                int4 c1 = *(const int4*)(sl + 4);
                int i0 = __builtin_amdgcn_readfirstlane(c0.x);
                int i1 = __builtin_amdgcn_readfirstlane(c0.y);
                int i2 = __builtin_amdgcn_readfirstlane(c0.z);
                int i3 = __builtin_amdgcn_readfirstlane(c0.w);
                int i4 = __builtin_amdgcn_readfirstlane(c1.x);
                int i5 = __builtin_amdgcn_readfirstlane(c1.y);
                int i6 = __builtin_amdgcn_readfirstlane(c1.z);
                int i7 = __builtin_amdgcn_readfirstlane(c1.w);
                unsigned v0 = hp[(long)i0 * 64 + lane], v1 = hp[(long)i1 * 64 + lane];
                unsigned v2 = hp[(long)i2 * 64 + lane], v3 = hp[(long)i3 * 64 + lane];
                unsigned v4 = hp[(long)i4 * 64 + lane], v5 = hp[(long)i5 * 64 + lane];
                unsigned v6 = hp[(long)i6 * 64 + lane], v7 = hp[(long)i7 * 64 + lane];
                float w0 = dinv[i0], w1 = dinv[i1], w2 = dinv[i2], w3 = dinv[i3];
                float w4 = dinv[i4], w5 = dinv[i5], w6 = dinv[i6], w7 = dinv[i7];
                int4 d0 = *(const int4*)(sl + 8);   // safe over-read (se follows csr)
                int4 d1 = *(const int4*)(sl + 12);
                for (int j = 8; j < m; j += 8) {
                    int t0 = __builtin_amdgcn_readfirstlane(d0.x);
                    int t1 = __builtin_amdgcn_readfirstlane(d0.y);
                    int t2 = __builtin_amdgcn_readfirstlane(d0.z);
                    int t3 = __builtin_amdgcn_readfirstlane(d0.w);
                    int t4 = __builtin_amdgcn_readfirstlane(d1.x);
                    int t5 = __builtin_amdgcn_readfirstlane(d1.y);
                    int t6 = __builtin_amdgcn_readfirstlane(d1.z);
                    int t7 = __builtin_amdgcn_readfirstlane(d1.w);
                    unsigned u0 = hp[(long)t0 * 64 + lane], u1 = hp[(long)t1 * 64 + lane];
                    unsigned u2 = hp[(long)t2 * 64 + lane], u3 = hp[(long)t3 * 64 + lane];
                    unsigned u4 = hp[(long)t4 * 64 + lane], u5 = hp[(long)t5 * 64 + lane];
                    unsigned u6 = hp[(long)t6 * 64 + lane], u7 = hp[(long)t7 * 64 + lane];
                    float q0 = dinv[t0], q1 = dinv[t1], q2 = dinv[t2], q3 = dinv[t3];
                    float q4 = dinv[t4], q5 = dinv[t5], q6 = dinv[t6], q7 = dinv[t7];
                    d0 = *(const int4*)(sl + j + 8);
                    d1 = *(const int4*)(sl + j + 12);
                    ACC8();
                    v0 = u0; v1 = u1; v2 = u2; v3 = u3; v4 = u4; v5 = u5; v6 = u6; v7 = u7;
                    w0 = q0; w1 = q1; w2 = q2; w3 = q3; w4 = q4; w5 = q5; w6 = q6; w7 = q7;
                }
                ACC8();
            }
            ox = fmaxf((a0x + a1x + a2x + a3x) * dn + bv.x, 0.f);
            oy = fmaxf((a0y + a1y + a2y + a3y) * dn + bv.y, 0.f);
        }
        bf16x2 st = {(__bf16)ox, (__bf16)oy};  // invalid nodes stash zeros
        stw[(wave * 4 + i) * 66 + lane] = *(unsigned*)&st;  // conflict-free (measured 0)
    }
    __syncthreads();

    // gemm2 from LDS: rows = 16 stashed nodes (B), wave w -> octile w of wf2 (A)
    int col = lane & 15, q = lane >> 4;
    const __bf16* srow = stash + col * 132;
    f32x4 acc = (f32x4){0.f, 0.f, 0.f, 0.f};
#pragma unroll
    for (int ks = 0; ks < 4; ks++) {
        bf16x8 bb = *(const bf16x8*)(srow + ks * 32 + q * 8);
        bf16x8 a = wf2[(ks * 4 + wave) * 64 + lane];
        acc = __builtin_amdgcn_mfma_f32_16x16x32_bf16(a, bb, acc, 0, 0, 0);
    }
    int node = n0 + col;
    if (node < N) {
        float dn2 = dinv[node];
        bf16x4 v;
#pragma unroll
        for (int r = 0; r < 4; r++) v[r] = (__bf16)(acc[r] * dn2);
        *(bf16x4*)(h2s + (long)node * 64 + (wave * 16 + q * 4)) = v;
    }
}
#undef ACC8

// ---------------- K4: agg64 (h2s pre-scaled by dinv[row]; sentinel row = 0) ----------------
// self term: h2s[n] already carries dinv[n]; final *dn gives dinv^2 (no extra *dn).
#define ACC8B()                                                                            \
    do {                                                                                   \
        a0 += __uint_as_float((unsigned)v0 << 16); a1 += __uint_as_float((unsigned)v1 << 16); \
        a2 += __uint_as_float((unsigned)v2 << 16); a3 += __uint_as_float((unsigned)v3 << 16); \
        a0 += __uint_as_float((unsigned)v4 << 16); a1 += __uint_as_float((unsigned)v5 << 16); \
        a2 += __uint_as_float((unsigned)v6 << 16); a3 += __uint_as_float((unsigned)v7 << 16); \
    } while (0)

__global__ __launch_bounds__(256) void agg64_kernel(const __bf16* __restrict__ hs,
                                                    const int* __restrict__ csr,
                                                    const int2* __restrict__ se,
                                                    const float* __restrict__ dinv,
                                                    const float* __restrict__ bias,
                                                    float* __restrict__ outp, int N) {
    int gid = blockIdx.x * TPB + threadIdx.x;
    int n = gid >> 6, lane = gid & 63;
    if (n >= N) return;
    int2 s_e = se[n];
    int start = s_e.x, m = s_e.y - s_e.x;    // m % 8 == 0
    float dn = dinv[n];
    const unsigned short* hp = (const unsigned short*)hs;  // row stride 64
    const int* sl = csr + start;
    float a0 = __uint_as_float(((unsigned)hp[(long)n * 64 + lane]) << 16);
    float a1 = 0.f, a2 = 0.f, a3 = 0.f;
    if (m > 0) {
        int4 c0 = *(const int4*)sl;
        int4 c1 = *(const int4*)(sl + 4);
        int i0 = __builtin_amdgcn_readfirstlane(c0.x);
        int i1 = __builtin_amdgcn_readfirstlane(c0.y);
        int i2 = __builtin_amdgcn_readfirstlane(c0.z);
        int i3 = __builtin_amdgcn_readfirstlane(c0.w);
        int i4 = __builtin_amdgcn_readfirstlane(c1.x);
        int i5 = __builtin_amdgcn_readfirstlane(c1.y);
        int i6 = __builtin_amdgcn_readfirstlane(c1.z);
        int i7 = __builtin_amdgcn_readfirstlane(c1.w);
        unsigned short v0 = hp[(long)i0 * 64 + lane], v1 = hp[(long)i1 * 64 + lane];
        unsigned short v2 = hp[(long)i2 * 64 + lane], v3 = hp[(long)i3 * 64 + lane];
        unsigned short v4 = hp[(long)i4 * 64 + lane], v5 = hp[(long)i5 * 64 + lane];
        unsigned short v6 = hp[(long)i6 * 64 + lane], v7 = hp[(long)i7 * 64 + lane];
        int4 d0 = *(const int4*)(sl + 8);
        int4 d1 = *(const int4*)(sl + 12);
        for (int j = 8; j < m; j += 8) {
            int t0 = __builtin_amdgcn_readfirstlane(d0.x);
            int t1 = __builtin_amdgcn_readfirstlane(d0.y);
            int t2 = __builtin_amdgcn_readfirstlane(d0.z);
            int t3 = __builtin_amdgcn_readfirstlane(d0.w);
            int t4 = __builtin_amdgcn_readfirstlane(d1.x);
            int t5 = __builtin_amdgcn_readfirstlane(d1.y);
            int t6 = __builtin_amdgcn_readfirstlane(d1.z);
            int t7 = __builtin_amdgcn_readfirstlane(d1.w);
            unsigned short u0 = hp[(long)t0 * 64 + lane], u1 = hp[(long)t1 * 64 + lane];
            unsigned short u2 = hp[(long)t2 * 64 + lane], u3 = hp[(long)t3 * 64 + lane];
            unsigned short u4 = hp[(long)t4 * 64 + lane], u5 = hp[(long)t5 * 64 + lane];
            unsigned short u6 = hp[(long)t6 * 64 + lane], u7 = hp[(long)t7 * 64 + lane];
            d0 = *(const int4*)(sl + j + 8);
            d1 = *(const int4*)(sl + j + 12);
            ACC8B();
            v0 = u0; v1 = u1; v2 = u2; v3 = u3; v4 = u4; v5 = u5; v6 = u6; v7 = u7;
        }
        ACC8B();
    }
    outp[(long)n * 64 + lane] = (a0 + a1 + a2 + a3) * dn + bias[lane];
}
#undef ACC8B

static inline int cdiv(long a, long b) { return (int)((a + b - 1) / b); }

extern "C" void kernel_launch(void* const* d_in, const int* in_sizes, int n_in,
                              void* d_out, int out_size, void* d_ws, size_t ws_size,
                              hipStream_t stream) {
    const float* x  = (const float*)d_in[0];
    const int*   ei = (const int*)d_in[1];
    const float* W1 = (const float*)d_in[2];
    const float* b1 = (const float*)d_in[3];
    const float* W2 = (const float*)d_in[4];
    const float* b2 = (const float*)d_in[5];

    const int IN_C = 256;
    const int N = in_sizes[0] / IN_C;   // 50000
    const int E = in_sizes[1] / 2;      // 800000
    const int* src = ei;
    const int* dst = ei + E;

    char* w = (char*)d_ws;
    size_t off = 0;
    auto alloc = [&](size_t bytes) { void* p = w + off; off = (off + bytes + 255) & ~255ull; return p; };
    __bf16*   h1u  = (__bf16*)alloc((size_t)(N + 1) * 128 * 2); // +sentinel row
    __bf16*   h2s  = (__bf16*)alloc((size_t)(N + 1) * 64 * 2);  // +sentinel row (zeroed)
    unsigned* ebuf = (unsigned*)alloc((size_t)NBKT * EB_CAP * 4);
    int*      csr  = (int*)alloc((size_t)NBKT * CSR_CAP * 4);
    int2*     se   = (int2*)alloc((size_t)N * 8);
    float*    dinv = (float*)alloc((size_t)(N + 1) * 4);        // +sentinel 0
    unsigned* gcnt = (unsigned*)alloc(NBKT * 4);
    __bf16*   wf1  = (__bf16*)alloc(64 * 64 * 8 * 2);
    __bf16*   wf2  = (__bf16*)alloc(16 * 64 * 8 * 2);

    // K0: clear bucket counters + sentinel rows (block 0) + pack W frags
    int wprepBlocks = cdiv(64 * 64 + 16 * 64, TPB);  // 20
    clear_wprep_kernel<<<1 + wprepBlocks, TPB, 0, stream>>>(gcnt, dinv, h2s, N,
                                                            W1, W2, wf1, wf2);

    // K1: bucket scatter (196 blocks x 4096 edges) | gemm1 (782 blocks, 64 rows each)
    int p1Blocks = cdiv(E, P1_EPB);                  // 196
    int gemmBlocks = cdiv(N, 64);                    // 782
    p1_gemm1_kernel<<<p1Blocks + gemmBlocks, TPB, 0, stream>>>(
        src, dst, E, p1Blocks, gcnt, ebuf, x, (const bf16x8*)wf1, h1u, N);

    // K2: per-bucket dense CSR + dinv + (start, start+pad), sentinel-padded
    csr_kernel<<<NBKT, TPB, 0, stream>>>(gcnt, ebuf, csr, se, dinv, N);

    // K3: layer-1 aggregate (+bias, relu) fused with gemm2 -> h2s
    agg128_gemm2_kernel<<<cdiv(N, 16), TPB, 0, stream>>>(h1u, csr, se, dinv, b1,
                                                         (const bf16x8*)wf2, h2s, N);

    // K4: layer-2 aggregate -> d_out (fp32)
    agg64_kernel<<<cdiv((long)N * 64, TPB), TPB, 0, stream>>>(h2s, csr, se, dinv, b2,
                                                              (float*)d_out, N);
}